// Round 2
// baseline (3023.678 us; speedup 1.0000x reference)
//
#include <hip/hip_runtime.h>

// GAT layer: messages = X@Wm^T; e = lrelu(sf[src]+st[dst]); softmax over dst;
// merged = segsum(alpha * messages[src]); out = sig(c)*(X@Wr^T) + relu(merged).
//
// Plan: f32 VALU GEMM (no fp32 MFMA on CDNA4) -> CSR-by-dst build (count/scan/
// scatter) -> one wave per node aggregates its row in registers (no f32 atomics).
// Softmax max-subtraction dropped (shift-invariant; e ~ N(0,1), exp bounded).

#define DD 128
#define NPB 32           // nodes per block in the GEMM kernel
#define LEAKY 0.01f

#define FMA4(A, XS, W)                                        \
  A.x = fmaf((XS), (W).x, A.x); A.y = fmaf((XS), (W).y, A.y); \
  A.z = fmaf((XS), (W).z, A.z); A.w = fmaf((XS), (W).w, A.w)

// ---------- tiny helpers ----------
__global__ void k_transpose2(const float* __restrict__ Wm, const float* __restrict__ Wr,
                             float* __restrict__ WTm, float* __restrict__ WTr) {
  int idx = blockIdx.x * blockDim.x + threadIdx.x;
  if (idx < DD * DD) {
    int j = idx >> 7, k = idx & (DD - 1);
    WTm[k * DD + j] = Wm[idx];   // WT[k][j] = W[j][k]
    WTr[k * DD + j] = Wr[idx];
  }
}

__global__ void k_zero(int* __restrict__ p, int n) {
  int i = blockIdx.x * blockDim.x + threadIdx.x;
  if (i < n) p[i] = 0;
}

// Detect whether the edges buffer is int64 (odd int32 words all zero) or int32.
__global__ void k_detect(const int* __restrict__ e, int* __restrict__ flag) {
  if (threadIdx.x == 0 && blockIdx.x == 0) {
    int all0 = 1;
    for (int i = 0; i < 64; ++i)
      if (e[2 * i + 1] != 0) { all0 = 0; break; }
    flag[0] = all0;  // 1 -> int64 layout
  }
}

// ---------- fused GEMM: messages + scores + passthrough ----------
// Block = 256 thr, 32 nodes. WT staged in LDS in two 64-row halves (stays
// under the 64 KiB static-LDS cap: 32K W + 16K X + 1K attn = 49 KiB).
__device__ __forceinline__ void gemm_phase(const float* __restrict__ WT,
                                           float* lds_w, const float* lds_x,
                                           int t, int j4, int g, float4 acc[4]) {
  float4* lw4 = (float4*)lds_w;
  const float4* lx4 = (const float4*)lds_x;
  acc[0] = acc[1] = acc[2] = acc[3] = make_float4(0.f, 0.f, 0.f, 0.f);
  for (int half = 0; half < 2; ++half) {
    __syncthreads();  // prior lds_w readers (and initial x staging) done
    const float4* wsrc = (const float4*)(WT + half * 64 * DD);
    for (int i = t; i < 2048; i += 256) lw4[i] = wsrc[i];
    __syncthreads();
    const int kb4 = half * 16;  // float4 index base into x rows
    for (int k = 0; k < 64; k += 4) {
      float4 w0 = lw4[(k + 0) * 32 + j4];
      float4 w1 = lw4[(k + 1) * 32 + j4];
      float4 w2 = lw4[(k + 2) * 32 + j4];
      float4 w3 = lw4[(k + 3) * 32 + j4];
#pragma unroll
      for (int b = 0; b < 4; ++b) {
        float4 xk = lx4[(g * 4 + b) * 32 + kb4 + (k >> 2)];
        FMA4(acc[b], xk.x, w0);
        FMA4(acc[b], xk.y, w1);
        FMA4(acc[b], xk.z, w2);
        FMA4(acc[b], xk.w, w3);
      }
    }
  }
}

__global__ __launch_bounds__(256) void k_msg(
    const float* __restrict__ x, const float* __restrict__ WTm,
    const float* __restrict__ WTr, const float* __restrict__ attn_w,
    const float* __restrict__ coef, int n_nodes,
    float* __restrict__ messages, float* __restrict__ s_from,
    float* __restrict__ s_to, float* __restrict__ out) {
  __shared__ float lds_w[64 * DD];    // 32 KiB (half of WT)
  __shared__ float lds_x[NPB * DD];   // 16 KiB
  __shared__ float lds_aw[2 * DD];    // 1 KiB
  const int t = threadIdx.x;
  const int base = blockIdx.x * NPB;
  const int nvalid = min(NPB, n_nodes - base);

  // stage X rows (flat copy, coalesced float4)
  const float4* xs = (const float4*)(x + (size_t)base * DD);
  float4* lx4 = (float4*)lds_x;
  const int nflt4 = nvalid * (DD / 4);
  for (int i = t; i < nflt4; i += 256) lx4[i] = xs[i];
  if (t < 2 * DD) lds_aw[t] = attn_w[t];

  const int j4 = t & 31;   // float4-column (outputs 4*j4..4*j4+3)
  const int g = t >> 5;    // node group (half-wave uniform)
  float4 acc[4];

  // ---- phase A: messages = X @ Wm^T, plus attention scores ----
  gemm_phase(WTm, lds_w, lds_x, t, j4, g, acc);
#pragma unroll
  for (int b = 0; b < 4; ++b) {
    int n = g * 4 + b;
    if (n < nvalid) {   // uniform across the 32-lane group
      int gn = base + n;
      float4 v = acc[b];
      ((float4*)(messages + (size_t)gn * DD))[j4] = v;
      float sf = v.x * lds_aw[4 * j4] + v.y * lds_aw[4 * j4 + 1] +
                 v.z * lds_aw[4 * j4 + 2] + v.w * lds_aw[4 * j4 + 3];
      float stv = v.x * lds_aw[DD + 4 * j4] + v.y * lds_aw[DD + 4 * j4 + 1] +
                  v.z * lds_aw[DD + 4 * j4 + 2] + v.w * lds_aw[DD + 4 * j4 + 3];
#pragma unroll
      for (int m = 16; m; m >>= 1) {
        sf += __shfl_xor(sf, m, 32);
        stv += __shfl_xor(stv, m, 32);
      }
      if (j4 == 0) { s_from[gn] = sf; s_to[gn] = stv; }
    }
  }

  // ---- phase B: passthrough = sig(c) * (X @ Wr^T) -> d_out ----
  const float sig = 1.f / (1.f + __expf(-coef[0]));
  gemm_phase(WTr, lds_w, lds_x, t, j4, g, acc);
#pragma unroll
  for (int b = 0; b < 4; ++b) {
    int n = g * 4 + b;
    if (n < nvalid) {
      int gn = base + n;
      float4 v = acc[b];
      v.x *= sig; v.y *= sig; v.z *= sig; v.w *= sig;
      ((float4*)(out + (size_t)gn * DD))[j4] = v;
    }
  }
}

// ---------- CSR build ----------
__global__ void k_count(const int* __restrict__ edges, int n_edges, int n_nodes,
                        const int* __restrict__ flag, int* __restrict__ deg) {
  int i = blockIdx.x * blockDim.x + threadIdx.x;
  if (i < n_edges) {
    int is64 = flag[0];
    int d = is64 ? edges[2 * n_edges + 2 * i] : edges[n_edges + i];
    if ((unsigned)d < (unsigned)n_nodes) atomicAdd(&deg[d], 1);
  }
}

__global__ __launch_bounds__(256) void k_scan_a(const int* __restrict__ deg, int n,
                                                int* __restrict__ outp,
                                                int* __restrict__ bsum) {
  __shared__ int lds[256];
  const int t = threadIdx.x;
  const int base = blockIdx.x * 1024 + t * 4;
  int v0 = 0, v1 = 0, v2 = 0, v3 = 0;
  if (base + 3 < n) {
    int4 q = *(const int4*)(deg + base);
    v0 = q.x; v1 = q.y; v2 = q.z; v3 = q.w;
  } else {
    if (base + 0 < n) v0 = deg[base + 0];
    if (base + 1 < n) v1 = deg[base + 1];
    if (base + 2 < n) v2 = deg[base + 2];
    if (base + 3 < n) v3 = deg[base + 3];
  }
  const int tsum = v0 + v1 + v2 + v3;
  int val = tsum;
  lds[t] = val;
  __syncthreads();
  for (int off = 1; off < 256; off <<= 1) {
    int a = (t >= off) ? lds[t - off] : 0;
    __syncthreads();
    val += a;
    lds[t] = val;
    __syncthreads();
  }
  int o0 = val - tsum;          // exclusive prefix for this thread's first elem
  int o1 = o0 + v0, o2 = o1 + v1, o3 = o2 + v2;
  if (base + 0 < n) outp[base + 0] = o0;
  if (base + 1 < n) outp[base + 1] = o1;
  if (base + 2 < n) outp[base + 2] = o2;
  if (base + 3 < n) outp[base + 3] = o3;
  if (t == 255) bsum[blockIdx.x] = val;  // block total
}

__global__ void k_scan_b(int* __restrict__ bsum, int nb) {
  __shared__ int lds[256];
  const int t = threadIdx.x;
  int v = (t < nb) ? bsum[t] : 0;
  int val = v;
  lds[t] = val;
  __syncthreads();
  for (int off = 1; off < 256; off <<= 1) {
    int a = (t >= off) ? lds[t - off] : 0;
    __syncthreads();
    val += a;
    lds[t] = val;
    __syncthreads();
  }
  if (t < nb) bsum[t] = val - v;  // exclusive
}

__global__ void k_scan_c(int* __restrict__ row_start, int* __restrict__ cursor,
                         const int* __restrict__ bsum, int n, int n_edges) {
  const int t = threadIdx.x;
  const int off = bsum[blockIdx.x];
  const int base = blockIdx.x * 1024 + t * 4;
#pragma unroll
  for (int c = 0; c < 4; ++c) {
    int idx = base + c;
    if (idx < n) {
      int r = row_start[idx] + off;
      row_start[idx] = r;
      cursor[idx] = r;
    }
  }
  if (blockIdx.x == 0 && t == 0) row_start[n] = n_edges;
}

__global__ void k_scatter(const int* __restrict__ edges, int n_edges, int n_nodes,
                          const int* __restrict__ flag, int* __restrict__ cursor,
                          int* __restrict__ srcs) {
  int i = blockIdx.x * blockDim.x + threadIdx.x;
  if (i < n_edges) {
    int is64 = flag[0];
    int d = is64 ? edges[2 * n_edges + 2 * i] : edges[n_edges + i];
    int s = is64 ? edges[2 * i] : edges[i];
    if ((unsigned)d < (unsigned)n_nodes) {
      int pos = atomicAdd(&cursor[d], 1);
      srcs[pos] = s;
    }
  }
}

// ---------- aggregation: one wave per node, row in registers ----------
__global__ __launch_bounds__(256) void k_agg(
    const int* __restrict__ row_start, const int* __restrict__ srcs,
    const float* __restrict__ s_from, const float* __restrict__ s_to,
    const float* __restrict__ messages, int n_nodes, float* __restrict__ out) {
  const int lane = threadIdx.x & 63;
  const int v = blockIdx.x * 4 + (threadIdx.x >> 6);
  if (v >= n_nodes) return;
  const int start = row_start[v];
  const int end = row_start[v + 1];
  if (start >= end) return;  // degree 0: d_out row already = passthrough
  const float st = s_to[v];

  float wsum = 0.f;
  float ax = 0.f, ay = 0.f;  // lane owns columns 2*lane, 2*lane+1
  for (int cbase = start; cbase < end; cbase += 64) {
    const int cnt = min(64, end - cbase);
    int s = 0;
    float w = 0.f;
    if (lane < cnt) {
      s = srcs[cbase + lane];
      if ((unsigned)s >= (unsigned)n_nodes) s = 0;
      float xx = s_from[s] + st;
      xx = (xx >= 0.f) ? xx : LEAKY * xx;
      w = __expf(xx);  // no max-sub: softmax shift-invariant, e is O(1)
    }
    wsum += w;
    for (int i = 0; i < cnt; ++i) {
      int si = __shfl(s, i, 64);
      float wi = __shfl(w, i, 64);
      const float2 m2 = ((const float2*)(messages + (size_t)si * DD))[lane];
      ax = fmaf(wi, m2.x, ax);
      ay = fmaf(wi, m2.y, ay);
    }
  }
#pragma unroll
  for (int m = 32; m; m >>= 1) wsum += __shfl_xor(wsum, m, 64);
  const float inv = 1.f / wsum;
  ax *= inv; ay *= inv;
  ax = (ax > 0.f) ? ax : 0.f;  // relu(merged)
  ay = (ay > 0.f) ? ay : 0.f;
  float2* orow = (float2*)(out + (size_t)v * DD);
  float2 po = orow[lane];      // passthrough written by k_msg
  orow[lane] = make_float2(po.x + ax, po.y + ay);
}

// ---------- host ----------
extern "C" void kernel_launch(void* const* d_in, const int* in_sizes, int n_in,
                              void* d_out, int out_size, void* d_ws, size_t ws_size,
                              hipStream_t stream) {
  const float* x = (const float*)d_in[0];
  const int* edges = (const int*)d_in[1];
  const float* Wm = (const float*)d_in[2];
  const float* aw = (const float*)d_in[3];
  const float* Wr = (const float*)d_in[4];
  const float* coef = (const float*)d_in[5];
  float* out = (float*)d_out;

  const int N = in_sizes[0] / DD;  // 100000
  const int E = in_sizes[1] / 2;   // 1600000

  // Workspace budget check: never scribble past d_ws (container-killer).
  const size_t need = ((size_t)N * DD * 4 + 256)   // messages
                    + 2 * ((size_t)N * 4 + 256)    // s_from, s_to
                    + 2 * ((size_t)DD * DD * 4 + 256)  // WTm, WTr
                    + 3 * ((size_t)N * 4 + 512)    // deg, row_start(+1), cursor
                    + 2048                          // bsum + flag
                    + (size_t)E * 4 + 256;          // srcs
  if (ws_size < need) return;  // refuse to run rather than corrupt memory

  char* w = (char*)d_ws;
  auto alloc = [&](size_t bytes) {
    char* p = w;
    w += (bytes + 255) & ~(size_t)255;
    return p;
  };
  float* messages = (float*)alloc((size_t)N * DD * 4);
  float* s_from   = (float*)alloc((size_t)N * 4);
  float* s_to     = (float*)alloc((size_t)N * 4);
  float* WTm      = (float*)alloc((size_t)DD * DD * 4);
  float* WTr      = (float*)alloc((size_t)DD * DD * 4);
  int*   deg      = (int*)alloc((size_t)N * 4);
  int*   row_start= (int*)alloc((size_t)(N + 1) * 4);
  int*   cursor   = (int*)alloc((size_t)N * 4);
  int*   bsum     = (int*)alloc(256 * 4);
  int*   flag     = (int*)alloc(256);
  int*   srcs     = (int*)alloc((size_t)E * 4);

  k_detect<<<1, 64, 0, stream>>>(edges, flag);
  k_transpose2<<<(DD * DD + 255) / 256, 256, 0, stream>>>(Wm, Wr, WTm, WTr);
  k_zero<<<(N + 255) / 256, 256, 0, stream>>>(deg, N);
  k_msg<<<(N + NPB - 1) / NPB, 256, 0, stream>>>(x, WTm, WTr, aw, coef, N,
                                                 messages, s_from, s_to, out);
  k_count<<<(E + 255) / 256, 256, 0, stream>>>(edges, E, N, flag, deg);
  const int nb1 = (N + 1023) / 1024;
  k_scan_a<<<nb1, 256, 0, stream>>>(deg, N, row_start, bsum);
  k_scan_b<<<1, 256, 0, stream>>>(bsum, nb1);
  k_scan_c<<<nb1, 256, 0, stream>>>(row_start, cursor, bsum, N, E);
  k_scatter<<<(E + 255) / 256, 256, 0, stream>>>(edges, E, N, flag, cursor, srcs);
  k_agg<<<(N + 3) / 4, 256, 0, stream>>>(row_start, srcs, s_from, s_to,
                                         messages, N, out);
}

// Round 3
// 543.682 us; speedup vs baseline: 5.5615x; 5.5615x over previous
//
#include <hip/hip_runtime.h>

// GAT layer: messages = X@Wm^T; e = lrelu(sf[src]+st[dst]); softmax over dst;
// merged = segsum(alpha * messages[src]); out = sig(c)*(X@Wr^T) + relu(merged).
//
// R2 fix: k_msg was 2.6ms from register-spill scratch traffic (256 VGPR,
// 6.4 GB of unintended HBM traffic, VALUBusy 3.6%). Rewrote the GEMM with
// named accumulators + modest unroll (no full k-loop unroll -> no spill) and
// 16 KiB W chunks (LDS 49->33 KiB, 4 blocks/CU).

#define DD 128
#define NPB 32           // nodes per block in the GEMM kernel
#define LEAKY 0.01f

#define FMA4(A, XS, W)                                        \
  A.x = fmaf((XS), (W).x, A.x); A.y = fmaf((XS), (W).y, A.y); \
  A.z = fmaf((XS), (W).z, A.z); A.w = fmaf((XS), (W).w, A.w)

// ---------- tiny helpers ----------
__global__ void k_transpose2(const float* __restrict__ Wm, const float* __restrict__ Wr,
                             float* __restrict__ WTm, float* __restrict__ WTr) {
  int idx = blockIdx.x * blockDim.x + threadIdx.x;
  if (idx < DD * DD) {
    int j = idx >> 7, k = idx & (DD - 1);
    WTm[k * DD + j] = Wm[idx];   // WT[k][j] = W[j][k]
    WTr[k * DD + j] = Wr[idx];
  }
}

__global__ void k_zero(int* __restrict__ p, int n) {
  int i = blockIdx.x * blockDim.x + threadIdx.x;
  if (i < n) p[i] = 0;
}

// Detect whether the edges buffer is int64 (odd int32 words all zero) or int32.
__global__ void k_detect(const int* __restrict__ e, int* __restrict__ flag) {
  if (threadIdx.x == 0 && blockIdx.x == 0) {
    int all0 = 1;
    for (int i = 0; i < 64; ++i)
      if (e[2 * i + 1] != 0) { all0 = 0; break; }
    flag[0] = all0;  // 1 -> int64 layout
  }
}

// ---------- fused GEMM: messages + scores + passthrough ----------
// Block = 256 thr, 32 nodes, 4 nodes x 4 cols per thread (1 flop/LDS-byte).
// W staged in four 32-k-row chunks of 16 KiB. Static LDS = 33 KiB.
__global__ __launch_bounds__(256) void k_msg(
    const float* __restrict__ x, const float* __restrict__ WTm,
    const float* __restrict__ WTr, const float* __restrict__ attn_w,
    const float* __restrict__ coef, int n_nodes,
    float* __restrict__ messages, float* __restrict__ s_from,
    float* __restrict__ s_to, float* __restrict__ out) {
  __shared__ float4 lw4[32 * 32];    // one chunk: 32 k-rows x 32 float4-cols, 16 KiB
  __shared__ float4 lx4[NPB * 32];   // 32 node rows x 32 float4, 16 KiB
  __shared__ float lds_aw[2 * DD];   // 1 KiB
  const int t = threadIdx.x;
  const int base = blockIdx.x * NPB;
  const int nvalid = min(NPB, n_nodes - base);

  // stage X rows (flat copy, coalesced float4)
  const float4* xs = (const float4*)(x + (size_t)base * DD);
  const int nflt4 = nvalid * 32;
  for (int i = t; i < nflt4; i += 256) lx4[i] = xs[i];
  if (t < 2 * DD) lds_aw[t] = attn_w[t];

  const int j4 = t & 31;   // float4-column (outputs 4*j4..4*j4+3)
  const int g = t >> 5;    // node group (half-wave uniform)
  const int r0 = (g * 4 + 0) * 32, r1 = r0 + 32, r2 = r1 + 32, r3 = r2 + 32;

  float4 a0, a1, a2, a3;

  // GEMM over one 128x128 weight: 4 chunks of 32 k-rows. Named accumulators,
  // bounded unroll -> ~90 live VGPRs (R1 version spilled: full unroll, 256+).
#define GEMM128(WT)                                                           \
  a0 = a1 = a2 = a3 = make_float4(0.f, 0.f, 0.f, 0.f);                        \
  _Pragma("unroll 1")                                                         \
  for (int chunk = 0; chunk < 4; ++chunk) {                                   \
    __syncthreads();                                                          \
    const float4* wsrc = (const float4*)((WT) + chunk * 32 * DD);             \
    lw4[t] = wsrc[t];                                                         \
    lw4[t + 256] = wsrc[t + 256];                                             \
    lw4[t + 512] = wsrc[t + 512];                                             \
    lw4[t + 768] = wsrc[t + 768];                                             \
    __syncthreads();                                                          \
    const int xb = chunk * 8;                                                 \
    _Pragma("unroll 2")                                                       \
    for (int k = 0; k < 32; k += 4) {                                         \
      float4 w0 = lw4[(k + 0) * 32 + j4];                                     \
      float4 w1 = lw4[(k + 1) * 32 + j4];                                     \
      float4 w2 = lw4[(k + 2) * 32 + j4];                                     \
      float4 w3 = lw4[(k + 3) * 32 + j4];                                     \
      float4 x0 = lx4[r0 + xb + (k >> 2)];                                    \
      float4 x1 = lx4[r1 + xb + (k >> 2)];                                    \
      float4 x2 = lx4[r2 + xb + (k >> 2)];                                    \
      float4 x3 = lx4[r3 + xb + (k >> 2)];                                    \
      FMA4(a0, x0.x, w0); FMA4(a0, x0.y, w1);                                 \
      FMA4(a0, x0.z, w2); FMA4(a0, x0.w, w3);                                 \
      FMA4(a1, x1.x, w0); FMA4(a1, x1.y, w1);                                 \
      FMA4(a1, x1.z, w2); FMA4(a1, x1.w, w3);                                 \
      FMA4(a2, x2.x, w0); FMA4(a2, x2.y, w1);                                 \
      FMA4(a2, x2.z, w2); FMA4(a2, x2.w, w3);                                 \
      FMA4(a3, x3.x, w0); FMA4(a3, x3.y, w1);                                 \
      FMA4(a3, x3.z, w2); FMA4(a3, x3.w, w3);                                 \
    }                                                                         \
  }

  // ---- phase A: messages = X @ Wm^T, plus attention scores ----
  GEMM128(WTm);
  {
    float4 av[4] = {a0, a1, a2, a3};
#pragma unroll
    for (int b = 0; b < 4; ++b) {
      int n = g * 4 + b;
      if (n < nvalid) {   // uniform across the 32-lane group
        int gn = base + n;
        float4 v = av[b];
        ((float4*)(messages + (size_t)gn * DD))[j4] = v;
        float sf = v.x * lds_aw[4 * j4] + v.y * lds_aw[4 * j4 + 1] +
                   v.z * lds_aw[4 * j4 + 2] + v.w * lds_aw[4 * j4 + 3];
        float stv = v.x * lds_aw[DD + 4 * j4] + v.y * lds_aw[DD + 4 * j4 + 1] +
                    v.z * lds_aw[DD + 4 * j4 + 2] + v.w * lds_aw[DD + 4 * j4 + 3];
#pragma unroll
        for (int m = 16; m; m >>= 1) {
          sf += __shfl_xor(sf, m, 32);
          stv += __shfl_xor(stv, m, 32);
        }
        if (j4 == 0) { s_from[gn] = sf; s_to[gn] = stv; }
      }
    }
  }

  // ---- phase B: passthrough = sig(c) * (X @ Wr^T) -> d_out ----
  const float sig = 1.f / (1.f + __expf(-coef[0]));
  GEMM128(WTr);
  {
    float4 av[4] = {a0, a1, a2, a3};
#pragma unroll
    for (int b = 0; b < 4; ++b) {
      int n = g * 4 + b;
      if (n < nvalid) {
        int gn = base + n;
        float4 v = av[b];
        v.x *= sig; v.y *= sig; v.z *= sig; v.w *= sig;
        ((float4*)(out + (size_t)gn * DD))[j4] = v;
      }
    }
  }
#undef GEMM128
}

// ---------- CSR build ----------
__global__ void k_count(const int* __restrict__ edges, int n_edges, int n_nodes,
                        const int* __restrict__ flag, int* __restrict__ deg) {
  int i = blockIdx.x * blockDim.x + threadIdx.x;
  if (i < n_edges) {
    int is64 = flag[0];
    int d = is64 ? edges[2 * n_edges + 2 * i] : edges[n_edges + i];
    if ((unsigned)d < (unsigned)n_nodes) atomicAdd(&deg[d], 1);
  }
}

__global__ __launch_bounds__(256) void k_scan_a(const int* __restrict__ deg, int n,
                                                int* __restrict__ outp,
                                                int* __restrict__ bsum) {
  __shared__ int lds[256];
  const int t = threadIdx.x;
  const int base = blockIdx.x * 1024 + t * 4;
  int v0 = 0, v1 = 0, v2 = 0, v3 = 0;
  if (base + 3 < n) {
    int4 q = *(const int4*)(deg + base);
    v0 = q.x; v1 = q.y; v2 = q.z; v3 = q.w;
  } else {
    if (base + 0 < n) v0 = deg[base + 0];
    if (base + 1 < n) v1 = deg[base + 1];
    if (base + 2 < n) v2 = deg[base + 2];
    if (base + 3 < n) v3 = deg[base + 3];
  }
  const int tsum = v0 + v1 + v2 + v3;
  int val = tsum;
  lds[t] = val;
  __syncthreads();
  for (int off = 1; off < 256; off <<= 1) {
    int a = (t >= off) ? lds[t - off] : 0;
    __syncthreads();
    val += a;
    lds[t] = val;
    __syncthreads();
  }
  int o0 = val - tsum;          // exclusive prefix for this thread's first elem
  int o1 = o0 + v0, o2 = o1 + v1, o3 = o2 + v2;
  if (base + 0 < n) outp[base + 0] = o0;
  if (base + 1 < n) outp[base + 1] = o1;
  if (base + 2 < n) outp[base + 2] = o2;
  if (base + 3 < n) outp[base + 3] = o3;
  if (t == 255) bsum[blockIdx.x] = val;  // block total
}

__global__ void k_scan_b(int* __restrict__ bsum, int nb) {
  __shared__ int lds[256];
  const int t = threadIdx.x;
  int v = (t < nb) ? bsum[t] : 0;
  int val = v;
  lds[t] = val;
  __syncthreads();
  for (int off = 1; off < 256; off <<= 1) {
    int a = (t >= off) ? lds[t - off] : 0;
    __syncthreads();
    val += a;
    lds[t] = val;
    __syncthreads();
  }
  if (t < nb) bsum[t] = val - v;  // exclusive
}

__global__ void k_scan_c(int* __restrict__ row_start, int* __restrict__ cursor,
                         const int* __restrict__ bsum, int n, int n_edges) {
  const int t = threadIdx.x;
  const int off = bsum[blockIdx.x];
  const int base = blockIdx.x * 1024 + t * 4;
#pragma unroll
  for (int c = 0; c < 4; ++c) {
    int idx = base + c;
    if (idx < n) {
      int r = row_start[idx] + off;
      row_start[idx] = r;
      cursor[idx] = r;
    }
  }
  if (blockIdx.x == 0 && t == 0) row_start[n] = n_edges;
}

__global__ void k_scatter(const int* __restrict__ edges, int n_edges, int n_nodes,
                          const int* __restrict__ flag, int* __restrict__ cursor,
                          int* __restrict__ srcs) {
  int i = blockIdx.x * blockDim.x + threadIdx.x;
  if (i < n_edges) {
    int is64 = flag[0];
    int d = is64 ? edges[2 * n_edges + 2 * i] : edges[n_edges + i];
    int s = is64 ? edges[2 * i] : edges[i];
    if ((unsigned)d < (unsigned)n_nodes) {
      int pos = atomicAdd(&cursor[d], 1);
      srcs[pos] = s;
    }
  }
}

// ---------- aggregation: one wave per node, row in registers ----------
__global__ __launch_bounds__(256) void k_agg(
    const int* __restrict__ row_start, const int* __restrict__ srcs,
    const float* __restrict__ s_from, const float* __restrict__ s_to,
    const float* __restrict__ messages, int n_nodes, float* __restrict__ out) {
  const int lane = threadIdx.x & 63;
  const int v = blockIdx.x * 4 + (threadIdx.x >> 6);
  if (v >= n_nodes) return;
  const int start = row_start[v];
  const int end = row_start[v + 1];
  if (start >= end) return;  // degree 0: d_out row already = passthrough
  const float st = s_to[v];

  float wsum = 0.f;
  float ax = 0.f, ay = 0.f;  // lane owns columns 2*lane, 2*lane+1
  for (int cbase = start; cbase < end; cbase += 64) {
    const int cnt = min(64, end - cbase);
    int s = 0;
    float w = 0.f;
    if (lane < cnt) {
      s = srcs[cbase + lane];
      if ((unsigned)s >= (unsigned)n_nodes) s = 0;
      float xx = s_from[s] + st;
      xx = (xx >= 0.f) ? xx : LEAKY * xx;
      w = __expf(xx);  // no max-sub: softmax shift-invariant, e is O(1)
    }
    wsum += w;
    for (int i = 0; i < cnt; ++i) {
      int si = __shfl(s, i, 64);
      float wi = __shfl(w, i, 64);
      const float2 m2 = ((const float2*)(messages + (size_t)si * DD))[lane];
      ax = fmaf(wi, m2.x, ax);
      ay = fmaf(wi, m2.y, ay);
    }
  }
#pragma unroll
  for (int m = 32; m; m >>= 1) wsum += __shfl_xor(wsum, m, 64);
  const float inv = 1.f / wsum;
  ax *= inv; ay *= inv;
  ax = (ax > 0.f) ? ax : 0.f;  // relu(merged)
  ay = (ay > 0.f) ? ay : 0.f;
  float2* orow = (float2*)(out + (size_t)v * DD);
  float2 po = orow[lane];      // passthrough written by k_msg
  orow[lane] = make_float2(po.x + ax, po.y + ay);
}

// ---------- host ----------
extern "C" void kernel_launch(void* const* d_in, const int* in_sizes, int n_in,
                              void* d_out, int out_size, void* d_ws, size_t ws_size,
                              hipStream_t stream) {
  const float* x = (const float*)d_in[0];
  const int* edges = (const int*)d_in[1];
  const float* Wm = (const float*)d_in[2];
  const float* aw = (const float*)d_in[3];
  const float* Wr = (const float*)d_in[4];
  const float* coef = (const float*)d_in[5];
  float* out = (float*)d_out;

  const int N = in_sizes[0] / DD;  // 100000
  const int E = in_sizes[1] / 2;   // 1600000

  // Workspace budget check: never scribble past d_ws (container-killer).
  const size_t need = ((size_t)N * DD * 4 + 256)   // messages
                    + 2 * ((size_t)N * 4 + 256)    // s_from, s_to
                    + 2 * ((size_t)DD * DD * 4 + 256)  // WTm, WTr
                    + 3 * ((size_t)N * 4 + 512)    // deg, row_start(+1), cursor
                    + 2048                          // bsum + flag
                    + (size_t)E * 4 + 256;          // srcs
  if (ws_size < need) return;  // refuse to run rather than corrupt memory

  char* w = (char*)d_ws;
  auto alloc = [&](size_t bytes) {
    char* p = w;
    w += (bytes + 255) & ~(size_t)255;
    return p;
  };
  float* messages = (float*)alloc((size_t)N * DD * 4);
  float* s_from   = (float*)alloc((size_t)N * 4);
  float* s_to     = (float*)alloc((size_t)N * 4);
  float* WTm      = (float*)alloc((size_t)DD * DD * 4);
  float* WTr      = (float*)alloc((size_t)DD * DD * 4);
  int*   deg      = (int*)alloc((size_t)N * 4);
  int*   row_start= (int*)alloc((size_t)(N + 1) * 4);
  int*   cursor   = (int*)alloc((size_t)N * 4);
  int*   bsum     = (int*)alloc(256 * 4);
  int*   flag     = (int*)alloc(256);
  int*   srcs     = (int*)alloc((size_t)E * 4);

  k_detect<<<1, 64, 0, stream>>>(edges, flag);
  k_transpose2<<<(DD * DD + 255) / 256, 256, 0, stream>>>(Wm, Wr, WTm, WTr);
  k_zero<<<(N + 255) / 256, 256, 0, stream>>>(deg, N);
  k_msg<<<(N + NPB - 1) / NPB, 256, 0, stream>>>(x, WTm, WTr, aw, coef, N,
                                                 messages, s_from, s_to, out);
  k_count<<<(E + 255) / 256, 256, 0, stream>>>(edges, E, N, flag, deg);
  const int nb1 = (N + 1023) / 1024;
  k_scan_a<<<nb1, 256, 0, stream>>>(deg, N, row_start, bsum);
  k_scan_b<<<1, 256, 0, stream>>>(bsum, nb1);
  k_scan_c<<<nb1, 256, 0, stream>>>(row_start, cursor, bsum, N, E);
  k_scatter<<<(E + 255) / 256, 256, 0, stream>>>(edges, E, N, flag, cursor, srcs);
  k_agg<<<(N + 3) / 4, 256, 0, stream>>>(row_start, srcs, s_from, s_to,
                                         messages, N, out);
}

// Round 4
// 486.632 us; speedup vs baseline: 6.2135x; 1.1172x over previous
//
#include <hip/hip_runtime.h>
#include <hip/hip_fp16.h>

// GAT layer: messages = X@Wm^T; e = lrelu(sf[src]+st[dst]); softmax over dst;
// merged = segsum(alpha * messages[src]); out = sig(c)*(X@Wr^T) + relu(merged).
//
// R3: k_agg is gather-BW-bound (418 MB L2-miss @3.2 TB/s). Gathered message
// rows now stored fp16 (half the bytes, f32 accumulate; scores stay f32).
// W_res==I detected on device -> passthrough = sig*X, skipping GEMM-B
// (full GEMM fallback kept). f32 messages buffer dropped entirely.

#define DD 128
#define NPB 32           // nodes per block in the GEMM kernel
#define LEAKY 0.01f

#define FMA4(A, XS, W)                                        \
  A.x = fmaf((XS), (W).x, A.x); A.y = fmaf((XS), (W).y, A.y); \
  A.z = fmaf((XS), (W).z, A.z); A.w = fmaf((XS), (W).w, A.w)

// ---------- tiny helpers ----------
__global__ void k_transpose2(const float* __restrict__ Wm, const float* __restrict__ Wr,
                             float* __restrict__ WTm, float* __restrict__ WTr) {
  int idx = blockIdx.x * blockDim.x + threadIdx.x;
  if (idx < DD * DD) {
    int j = idx >> 7, k = idx & (DD - 1);
    WTm[k * DD + j] = Wm[idx];   // WT[k][j] = W[j][k]
    WTr[k * DD + j] = Wr[idx];
  }
}

__global__ void k_zero(int* __restrict__ p, int n) {
  int i = blockIdx.x * blockDim.x + threadIdx.x;
  if (i < n) p[i] = 0;
}

// Detect whether the edges buffer is int64 (odd int32 words all zero) or int32.
__global__ void k_detect(const int* __restrict__ e, int* __restrict__ flag) {
  if (threadIdx.x == 0 && blockIdx.x == 0) {
    int all0 = 1;
    for (int i = 0; i < 64; ++i)
      if (e[2 * i + 1] != 0) { all0 = 0; break; }
    flag[0] = all0;  // 1 -> int64 layout
  }
}

// Exact check: is W_res the identity? (one block, 256 threads)
__global__ void k_eye(const float* __restrict__ Wr, int* __restrict__ eyeflag) {
  __shared__ int ok_s;
  if (threadIdx.x == 0) ok_s = 1;
  __syncthreads();
  int ok = 1;
  for (int i = threadIdx.x; i < DD * DD; i += 256) {
    float expect = ((i >> 7) == (i & (DD - 1))) ? 1.f : 0.f;
    if (Wr[i] != expect) ok = 0;
  }
  if (!ok) ok_s = 0;  // benign race: all writers write 0
  __syncthreads();
  if (threadIdx.x == 0) eyeflag[0] = ok_s;
}

// ---------- fused GEMM: messages + scores + passthrough ----------
// Block = 256 thr, 32 nodes, 4 nodes x 4 cols per thread.
// W staged in four 32-k-row chunks of 16 KiB. Static LDS = 33 KiB.
__global__ __launch_bounds__(256) void k_msg(
    const float* __restrict__ x, const float* __restrict__ WTm,
    const float* __restrict__ WTr, const float* __restrict__ attn_w,
    const float* __restrict__ coef, const int* __restrict__ eyeflag, int n_nodes,
    __half* __restrict__ mh, float* __restrict__ s_from,
    float* __restrict__ s_to, float* __restrict__ out) {
  __shared__ float4 lw4[32 * 32];    // one chunk: 32 k-rows x 32 float4-cols, 16 KiB
  __shared__ float4 lx4[NPB * 32];   // 32 node rows x 32 float4, 16 KiB
  __shared__ float lds_aw[2 * DD];   // 1 KiB
  const int t = threadIdx.x;
  const int base = blockIdx.x * NPB;
  const int nvalid = min(NPB, n_nodes - base);

  // stage X rows (flat copy, coalesced float4)
  const float4* xs = (const float4*)(x + (size_t)base * DD);
  const int nflt4 = nvalid * 32;
  for (int i = t; i < nflt4; i += 256) lx4[i] = xs[i];
  if (t < 2 * DD) lds_aw[t] = attn_w[t];

  const int j4 = t & 31;   // float4-column (outputs 4*j4..4*j4+3)
  const int g = t >> 5;    // node group (half-wave uniform)
  const int r0 = (g * 4 + 0) * 32, r1 = r0 + 32, r2 = r1 + 32, r3 = r2 + 32;

  float4 a0, a1, a2, a3;

  // GEMM over one 128x128 weight: 4 chunks of 32 k-rows. Named accumulators,
  // bounded unroll -> no spill (R1 lesson: full unroll hit 256 VGPR + scratch).
#define GEMM128(WT)                                                           \
  a0 = a1 = a2 = a3 = make_float4(0.f, 0.f, 0.f, 0.f);                        \
  _Pragma("unroll 1")                                                         \
  for (int chunk = 0; chunk < 4; ++chunk) {                                   \
    __syncthreads();                                                          \
    const float4* wsrc = (const float4*)((WT) + chunk * 32 * DD);             \
    lw4[t] = wsrc[t];                                                         \
    lw4[t + 256] = wsrc[t + 256];                                             \
    lw4[t + 512] = wsrc[t + 512];                                             \
    lw4[t + 768] = wsrc[t + 768];                                             \
    __syncthreads();                                                          \
    const int xb = chunk * 8;                                                 \
    _Pragma("unroll 2")                                                       \
    for (int k = 0; k < 32; k += 4) {                                         \
      float4 w0 = lw4[(k + 0) * 32 + j4];                                     \
      float4 w1 = lw4[(k + 1) * 32 + j4];                                     \
      float4 w2 = lw4[(k + 2) * 32 + j4];                                     \
      float4 w3 = lw4[(k + 3) * 32 + j4];                                     \
      float4 x0 = lx4[r0 + xb + (k >> 2)];                                    \
      float4 x1 = lx4[r1 + xb + (k >> 2)];                                    \
      float4 x2 = lx4[r2 + xb + (k >> 2)];                                    \
      float4 x3 = lx4[r3 + xb + (k >> 2)];                                    \
      FMA4(a0, x0.x, w0); FMA4(a0, x0.y, w1);                                 \
      FMA4(a0, x0.z, w2); FMA4(a0, x0.w, w3);                                 \
      FMA4(a1, x1.x, w0); FMA4(a1, x1.y, w1);                                 \
      FMA4(a1, x1.z, w2); FMA4(a1, x1.w, w3);                                 \
      FMA4(a2, x2.x, w0); FMA4(a2, x2.y, w1);                                 \
      FMA4(a2, x2.z, w2); FMA4(a2, x2.w, w3);                                 \
      FMA4(a3, x3.x, w0); FMA4(a3, x3.y, w1);                                 \
      FMA4(a3, x3.z, w2); FMA4(a3, x3.w, w3);                                 \
    }                                                                         \
  }

  // ---- phase A: messages = X @ Wm^T (fp16 store), plus attention scores ----
  GEMM128(WTm);
  {
    float4 av[4] = {a0, a1, a2, a3};
#pragma unroll
    for (int b = 0; b < 4; ++b) {
      int n = g * 4 + b;
      if (n < nvalid) {   // uniform across the 32-lane group
        int gn = base + n;
        float4 v = av[b];
        union { __half2 h2[2]; uint2 u; } pk;
        pk.h2[0] = __floats2half2_rn(v.x, v.y);
        pk.h2[1] = __floats2half2_rn(v.z, v.w);
        ((uint2*)(mh + (size_t)gn * DD))[j4] = pk.u;
        float sf = v.x * lds_aw[4 * j4] + v.y * lds_aw[4 * j4 + 1] +
                   v.z * lds_aw[4 * j4 + 2] + v.w * lds_aw[4 * j4 + 3];
        float stv = v.x * lds_aw[DD + 4 * j4] + v.y * lds_aw[DD + 4 * j4 + 1] +
                    v.z * lds_aw[DD + 4 * j4 + 2] + v.w * lds_aw[DD + 4 * j4 + 3];
#pragma unroll
        for (int m = 16; m; m >>= 1) {
          sf += __shfl_xor(sf, m, 32);
          stv += __shfl_xor(stv, m, 32);
        }
        if (j4 == 0) { s_from[gn] = sf; s_to[gn] = stv; }
      }
    }
  }

  // ---- phase B: passthrough = sig(c) * (X @ Wr^T) -> d_out ----
  const float sig = 1.f / (1.f + __expf(-coef[0]));
  if (eyeflag[0]) {
    // W_res == I (the init in the reference): passthrough = sig * x.
    // lds_x is still intact (never overwritten after initial stage).
    float4* od = (float4*)(out + (size_t)base * DD);
    for (int i = t; i < nflt4; i += 256) {
      float4 v = lx4[i];
      v.x *= sig; v.y *= sig; v.z *= sig; v.w *= sig;
      od[i] = v;
    }
  } else {
    GEMM128(WTr);
    float4 av[4] = {a0, a1, a2, a3};
#pragma unroll
    for (int b = 0; b < 4; ++b) {
      int n = g * 4 + b;
      if (n < nvalid) {
        int gn = base + n;
        float4 v = av[b];
        v.x *= sig; v.y *= sig; v.z *= sig; v.w *= sig;
        ((float4*)(out + (size_t)gn * DD))[j4] = v;
      }
    }
  }
#undef GEMM128
}

// ---------- CSR build ----------
__global__ void k_count(const int* __restrict__ edges, int n_edges, int n_nodes,
                        const int* __restrict__ flag, int* __restrict__ deg) {
  int i = blockIdx.x * blockDim.x + threadIdx.x;
  if (i < n_edges) {
    int is64 = flag[0];
    int d = is64 ? edges[2 * n_edges + 2 * i] : edges[n_edges + i];
    if ((unsigned)d < (unsigned)n_nodes) atomicAdd(&deg[d], 1);
  }
}

__global__ __launch_bounds__(256) void k_scan_a(const int* __restrict__ deg, int n,
                                                int* __restrict__ outp,
                                                int* __restrict__ bsum) {
  __shared__ int lds[256];
  const int t = threadIdx.x;
  const int base = blockIdx.x * 1024 + t * 4;
  int v0 = 0, v1 = 0, v2 = 0, v3 = 0;
  if (base + 3 < n) {
    int4 q = *(const int4*)(deg + base);
    v0 = q.x; v1 = q.y; v2 = q.z; v3 = q.w;
  } else {
    if (base + 0 < n) v0 = deg[base + 0];
    if (base + 1 < n) v1 = deg[base + 1];
    if (base + 2 < n) v2 = deg[base + 2];
    if (base + 3 < n) v3 = deg[base + 3];
  }
  const int tsum = v0 + v1 + v2 + v3;
  int val = tsum;
  lds[t] = val;
  __syncthreads();
  for (int off = 1; off < 256; off <<= 1) {
    int a = (t >= off) ? lds[t - off] : 0;
    __syncthreads();
    val += a;
    lds[t] = val;
    __syncthreads();
  }
  int o0 = val - tsum;          // exclusive prefix for this thread's first elem
  int o1 = o0 + v0, o2 = o1 + v1, o3 = o2 + v2;
  if (base + 0 < n) outp[base + 0] = o0;
  if (base + 1 < n) outp[base + 1] = o1;
  if (base + 2 < n) outp[base + 2] = o2;
  if (base + 3 < n) outp[base + 3] = o3;
  if (t == 255) bsum[blockIdx.x] = val;  // block total
}

__global__ void k_scan_b(int* __restrict__ bsum, int nb) {
  __shared__ int lds[256];
  const int t = threadIdx.x;
  int v = (t < nb) ? bsum[t] : 0;
  int val = v;
  lds[t] = val;
  __syncthreads();
  for (int off = 1; off < 256; off <<= 1) {
    int a = (t >= off) ? lds[t - off] : 0;
    __syncthreads();
    val += a;
    lds[t] = val;
    __syncthreads();
  }
  if (t < nb) bsum[t] = val - v;  // exclusive
}

__global__ void k_scan_c(int* __restrict__ row_start, int* __restrict__ cursor,
                         const int* __restrict__ bsum, int n, int n_edges) {
  const int t = threadIdx.x;
  const int off = bsum[blockIdx.x];
  const int base = blockIdx.x * 1024 + t * 4;
#pragma unroll
  for (int c = 0; c < 4; ++c) {
    int idx = base + c;
    if (idx < n) {
      int r = row_start[idx] + off;
      row_start[idx] = r;
      cursor[idx] = r;
    }
  }
  if (blockIdx.x == 0 && t == 0) row_start[n] = n_edges;
}

__global__ void k_scatter(const int* __restrict__ edges, int n_edges, int n_nodes,
                          const int* __restrict__ flag, int* __restrict__ cursor,
                          int* __restrict__ srcs) {
  int i = blockIdx.x * blockDim.x + threadIdx.x;
  if (i < n_edges) {
    int is64 = flag[0];
    int d = is64 ? edges[2 * n_edges + 2 * i] : edges[n_edges + i];
    int s = is64 ? edges[2 * i] : edges[i];
    if ((unsigned)d < (unsigned)n_nodes) {
      int pos = atomicAdd(&cursor[d], 1);
      srcs[pos] = s;
    }
  }
}

// ---------- aggregation: one wave per node, fp16 gather, f32 accumulate ----------
__global__ __launch_bounds__(256) void k_agg(
    const int* __restrict__ row_start, const int* __restrict__ srcs,
    const float* __restrict__ s_from, const float* __restrict__ s_to,
    const __half* __restrict__ mh, int n_nodes, float* __restrict__ out) {
  const int lane = threadIdx.x & 63;
  const int v = blockIdx.x * 4 + (threadIdx.x >> 6);
  if (v >= n_nodes) return;
  const int start = row_start[v];
  const int end = row_start[v + 1];
  if (start >= end) return;  // degree 0: d_out row already = passthrough
  const float st = s_to[v];

  float wsum = 0.f;
  float ax = 0.f, ay = 0.f;  // lane owns columns 2*lane, 2*lane+1
  for (int cbase = start; cbase < end; cbase += 64) {
    const int cnt = min(64, end - cbase);
    int s = 0;
    float w = 0.f;
    if (lane < cnt) {
      s = srcs[cbase + lane];
      if ((unsigned)s >= (unsigned)n_nodes) s = 0;
      float xx = s_from[s] + st;
      xx = (xx >= 0.f) ? xx : LEAKY * xx;
      w = __expf(xx);  // no max-sub: softmax shift-invariant, e is O(1)
    }
    wsum += w;
#pragma unroll 4
    for (int i = 0; i < cnt; ++i) {
      int si = __shfl(s, i, 64);
      float wi = __shfl(w, i, 64);
      const __half2 m2h = ((const __half2*)(mh + (size_t)si * DD))[lane];
      const float2 mf = __half22float2(m2h);
      ax = fmaf(wi, mf.x, ax);
      ay = fmaf(wi, mf.y, ay);
    }
  }
#pragma unroll
  for (int m = 32; m; m >>= 1) wsum += __shfl_xor(wsum, m, 64);
  const float inv = 1.f / wsum;
  ax *= inv; ay *= inv;
  ax = (ax > 0.f) ? ax : 0.f;  // relu(merged)
  ay = (ay > 0.f) ? ay : 0.f;
  float2* orow = (float2*)(out + (size_t)v * DD);
  float2 po = orow[lane];      // passthrough written by k_msg
  orow[lane] = make_float2(po.x + ax, po.y + ay);
}

// ---------- host ----------
extern "C" void kernel_launch(void* const* d_in, const int* in_sizes, int n_in,
                              void* d_out, int out_size, void* d_ws, size_t ws_size,
                              hipStream_t stream) {
  const float* x = (const float*)d_in[0];
  const int* edges = (const int*)d_in[1];
  const float* Wm = (const float*)d_in[2];
  const float* aw = (const float*)d_in[3];
  const float* Wr = (const float*)d_in[4];
  const float* coef = (const float*)d_in[5];
  float* out = (float*)d_out;

  const int N = in_sizes[0] / DD;  // 100000
  const int E = in_sizes[1] / 2;   // 1600000

  // Workspace budget check: never scribble past d_ws (container-killer).
  const size_t need = ((size_t)N * DD * 2 + 256)   // mh (fp16 messages)
                    + 2 * ((size_t)N * 4 + 256)    // s_from, s_to
                    + 2 * ((size_t)DD * DD * 4 + 256)  // WTm, WTr
                    + 3 * ((size_t)N * 4 + 512)    // deg, row_start(+1), cursor
                    + 2048                          // bsum + flags
                    + (size_t)E * 4 + 256;          // srcs
  if (ws_size < need) return;  // refuse to run rather than corrupt memory

  char* w = (char*)d_ws;
  auto alloc = [&](size_t bytes) {
    char* p = w;
    w += (bytes + 255) & ~(size_t)255;
    return p;
  };
  __half* mh     = (__half*)alloc((size_t)N * DD * 2);
  float* s_from  = (float*)alloc((size_t)N * 4);
  float* s_to    = (float*)alloc((size_t)N * 4);
  float* WTm     = (float*)alloc((size_t)DD * DD * 4);
  float* WTr     = (float*)alloc((size_t)DD * DD * 4);
  int*   deg     = (int*)alloc((size_t)N * 4);
  int*   row_start = (int*)alloc((size_t)(N + 1) * 4);
  int*   cursor  = (int*)alloc((size_t)N * 4);
  int*   bsum    = (int*)alloc(256 * 4);
  int*   flag    = (int*)alloc(256);   // flag[0]=int64 layout, flag[1]=Wr==I
  int*   srcs    = (int*)alloc((size_t)E * 4);

  k_detect<<<1, 64, 0, stream>>>(edges, flag);
  k_eye<<<1, 256, 0, stream>>>(Wr, flag + 1);
  k_transpose2<<<(DD * DD + 255) / 256, 256, 0, stream>>>(Wm, Wr, WTm, WTr);
  k_zero<<<(N + 255) / 256, 256, 0, stream>>>(deg, N);
  k_msg<<<(N + NPB - 1) / NPB, 256, 0, stream>>>(x, WTm, WTr, aw, coef, flag + 1,
                                                 N, mh, s_from, s_to, out);
  k_count<<<(E + 255) / 256, 256, 0, stream>>>(edges, E, N, flag, deg);
  const int nb1 = (N + 1023) / 1024;
  k_scan_a<<<nb1, 256, 0, stream>>>(deg, N, row_start, bsum);
  k_scan_b<<<1, 256, 0, stream>>>(bsum, nb1);
  k_scan_c<<<nb1, 256, 0, stream>>>(row_start, cursor, bsum, N, E);
  k_scatter<<<(E + 255) / 256, 256, 0, stream>>>(edges, E, N, flag, cursor, srcs);
  k_agg<<<(N + 3) / 4, 256, 0, stream>>>(row_start, srcs, s_from, s_to,
                                         mh, N, out);
}